// Round 7
// baseline (73.133 us; speedup 1.0000x reference)
//
#include <hip/hip_runtime.h>
#include <math.h>

#define IN_F  256
#define OUT_F 256
#define OTILE 64      // o per block (lane = o)
#define BTILE 16      // b per block (4 per wave)
#define NTH   256

// out[b,o] = (1 + min_i((x-1)*pe)) * n0 + (-1 + max_i((x-1)*pe + 2*pe)) * n1
// pe = sigmoid(w0-w1) per (o,i); n0 = sigmoid(pw0-pw1); n1 = 1-n0.
// (x-1)*pe computed as fma(x, pe, -pe): x stays wave-uniform in SGPRs (s_load),
// pe comes from XOR-swizzled LDS (lane L reads row L, ds_read_b128).
__global__ __launch_bounds__(NTH, 2)
void den_kernel(const float* __restrict__ x,
                const float* __restrict__ pew,
                const float* __restrict__ pnw,
                float* __restrict__ out)
{
    __shared__ float pe_lds[OTILE * IN_F];   // 64 KB; row o at byte 1024*o, bytes XOR'd by ((o&7)<<4)

    const int tid = threadIdx.x;
    const int b0  = blockIdx.x * BTILE;
    const int o0  = blockIdx.y * OTILE;

    // ---- stage pe = sigmoid(w1-w0 -> rcp(1+e)) for 64 o x 256 i, swizzled ----
    {
        const int r16 = tid >> 4;            // 0..15: row within group of 16
        const int c   = tid & 15;            // 0..15: float4 chunk (lanes 0-15 contiguous 256B)
        for (int rg = 0; rg < 4; ++rg) {
            const int o  = rg * 16 + r16;    // 0..63
            const int xm = (o & 7) << 4;
            const float4* wp = reinterpret_cast<const float4*>(pew + (size_t)(o0 + o) * (IN_F * 2));
            char* rowp = reinterpret_cast<char*>(&pe_lds[o * IN_F]);
            #pragma unroll
            for (int k = 0; k < 8; ++k) {
                float4 w = wp[k * 16 + c];   // (w0_i, w1_i, w0_{i+1}, w1_{i+1})
                float pe0 = __builtin_amdgcn_rcpf(1.0f + __expf(w.y - w.x));
                float pe1 = __builtin_amdgcn_rcpf(1.0f + __expf(w.w - w.z));
                const int byteoff = (8 * (k * 16 + c)) ^ xm;   // 8B-aligned stays 8B-aligned
                *reinterpret_cast<float2*>(rowp + byteoff) = make_float2(pe0, pe1);
            }
        }
    }
    __syncthreads();   // the only barrier

    const int lane = tid & 63;                                  // lane = o offset
    const int wid  = __builtin_amdgcn_readfirstlane(tid >> 6);  // wave id 0..3 (forced SGPR)
    const int bb0  = b0 + wid * 4;                              // 4 b-rows per wave
    const char* rowp = reinterpret_cast<const char*>(&pe_lds[lane * IN_F]);
    const int xm = (lane & 7) << 4;

    float mn[4], mx[4];
    #pragma unroll
    for (int j = 0; j < 4; ++j) { mn[j] = INFINITY; mx[j] = -INFINITY; }

    const float* xr0 = x + (size_t)bb0 * IN_F;   // wave-uniform base

    // ---- main loop: 64 chunks of 4 i; per chunk: 1 swizzled ds_read_b128 + 4 uniform s_load x4 ----
    #pragma unroll 4
    for (int c = 0; c < 64; ++c) {
        float4 pv = *reinterpret_cast<const float4*>(rowp + ((16 * c) ^ xm));
        #pragma unroll
        for (int j = 0; j < 4; ++j) {
            float4 xv = *reinterpret_cast<const float4*>(xr0 + j * IN_F + 4 * c);  // uniform -> s_load_dwordx4
            // t = (x-1)*pe = fma(x, pe, -pe);  u = t + 2*pe
            float t0 = __builtin_fmaf(xv.x, pv.x, -pv.x);
            float t1 = __builtin_fmaf(xv.y, pv.y, -pv.y);
            float t2 = __builtin_fmaf(xv.z, pv.z, -pv.z);
            float t3 = __builtin_fmaf(xv.w, pv.w, -pv.w);
            float u0 = __builtin_fmaf(2.0f, pv.x, t0);
            float u1 = __builtin_fmaf(2.0f, pv.y, t1);
            float u2 = __builtin_fmaf(2.0f, pv.z, t2);
            float u3 = __builtin_fmaf(2.0f, pv.w, t3);
            mn[j] = fminf(fminf(mn[j], t0), t1);   // -> v_min3_f32
            mn[j] = fminf(fminf(mn[j], t2), t3);
            mx[j] = fmaxf(fmaxf(mx[j], u0), u1);   // -> v_max3_f32
            mx[j] = fmaxf(fmaxf(mx[j], u2), u3);
        }
    }

    // ---- epilogue: node softmax + combine; coalesced b32 stores ----
    const int o = o0 + lane;
    float2 nw = *reinterpret_cast<const float2*>(pnw + 2 * (size_t)o);
    float n0 = __builtin_amdgcn_rcpf(1.0f + __expf(nw.y - nw.x));
    float n1 = 1.0f - n0;
    #pragma unroll
    for (int j = 0; j < 4; ++j) {
        out[(size_t)(bb0 + j) * OUT_F + o] = (mn[j] + 1.0f) * n0 + (mx[j] - 1.0f) * n1;
    }
}

extern "C" void kernel_launch(void* const* d_in, const int* in_sizes, int n_in,
                              void* d_out, int out_size, void* d_ws, size_t ws_size,
                              hipStream_t stream) {
    (void)d_ws; (void)ws_size; (void)n_in; (void)out_size;
    const float* x   = (const float*)d_in[0];
    const float* pew = (const float*)d_in[1];
    const float* pnw = (const float*)d_in[2];
    float* out = (float*)d_out;
    const int B = in_sizes[0] / IN_F;          // 2048
    dim3 grid(B / BTILE, OUT_F / OTILE);       // 128 x 4 = 512 blocks (2/CU)
    den_kernel<<<grid, NTH, 0, stream>>>(x, pew, pnw, out);
}